// Round 4
// baseline (275.628 us; speedup 1.0000x reference)
//
#include <hip/hip_runtime.h>

// Problem constants (B,N,T,F,H,R) = (32,1024,32,5,64,5)
constexpr int Bc = 32, Nc = 1024, Tc = 32, Fc = 5, Hc = 64;
constexpr int BNc = Bc * Nc;   // 32768 sequences

#define DEVFN __device__ __forceinline__

typedef _Float16 f16x8 __attribute__((ext_vector_type(8)));
typedef _Float16 f16x4 __attribute__((ext_vector_type(4)));
typedef float    f32x16 __attribute__((ext_vector_type(16)));

DEVFN float fast_rcp(float x) { return __builtin_amdgcn_rcpf(x); }
DEVFN float sigm(float x) { return fast_rcp(1.f + __expf(-x)); }
DEVFN float tanh_fast(float x) { return 1.f - 2.f * fast_rcp(__expf(2.f * x) + 1.f); }

// ---------------- Kernel 1: fused LSTM + temporal attention (MFMA) ----------
// Block = 128 thr (2 waves) x 32 seqs; wave w owns hidden units [32w, 32w+32).
// Per t: D[j][m] = W'[j][k] * B[k][m] (K=80: h(64)|x(5)|1|pad) via
// mfma_f32_32x32x16_f16; wave w computes gate tiles jt = 2g+w, so every lane's
// 16 owned (unit,gate) quads are lane-local for the c/h update.
// Cross-wave h exchange: double-buffered fp16 LDS, XOR-swizzled 8B chunks
// (2-way bank aliasing = free), one barrier per t.
__global__ __launch_bounds__(128, 2) void lstm_attn_kernel(
    const float* __restrict__ x,      // [BN, T, F]
    const float* __restrict__ Wih,    // [4H, F]
    const float* __restrict__ Whh,    // [4H, H]
    const float* __restrict__ bih,    // [4H]
    const float* __restrict__ bhh,    // [4H]
    const float* __restrict__ attn_w, // [H]
    const float* __restrict__ attn_b, // [1]
    _Float16* __restrict__ E16,       // [B*N, H] fp16 row-major
    _Float16* __restrict__ ET)        // [B][H][N] fp16 transposed
{
    constexpr int XP = 164;                     // x pitch (halves)
    __shared__ __align__(16) _Float16 xs[32 * XP];   // 10.5 KB; aliased w/ es
    __shared__ __align__(16) _Float16 hb[2][32 * 64];// 8 KB h exchange
    __shared__ float ap[2][32];                 // attn partials per wave
    float* es = (float*)xs;                     // [32][65] epilogue bounce

    const int tid  = threadIdx.x;
    const int w    = tid >> 6;                  // wave id (0,1)
    const int lane = tid & 63;
    const int m    = lane & 31;                 // seq column
    const int hi   = lane >> 5;

    // ---- stage x (fp32 -> fp16 LDS) ----
    const float* xg = x + (size_t)blockIdx.x * 32 * Tc * Fc;
    for (int i = tid; i < 32 * 160; i += 128) {
        int mm = i / 160, o = i - mm * 160;
        xs[mm * XP + o] = (_Float16)xg[i];
    }
    // zero h buffer 0
    for (int i = tid; i < 1024; i += 128) ((uint*)&hb[0][0])[i] = 0u;

    // ---- preload A fragments: af[g][kt], jt = 2g+w, row j = 32*jt + m ----
    f16x8 af[4][5];
    #pragma unroll
    for (int g = 0; g < 4; ++g) {
        const int j = 32 * (2 * g + w) + m;     // = 64g + 32w + m
        #pragma unroll
        for (int kt = 0; kt < 4; ++kt) {
            const float* wp = Whh + j * 64 + kt * 16 + 8 * hi;
            float4 u0 = *(const float4*)wp;
            float4 u1 = *(const float4*)(wp + 4);
            af[g][kt] = f16x8{(_Float16)u0.x, (_Float16)u0.y, (_Float16)u0.z, (_Float16)u0.w,
                              (_Float16)u1.x, (_Float16)u1.y, (_Float16)u1.z, (_Float16)u1.w};
        }
        float v[8];
        #pragma unroll
        for (int e = 0; e < 5; ++e) v[e] = Wih[j * Fc + e];
        v[5] = bih[j] + bhh[j]; v[6] = 0.f; v[7] = 0.f;
        #pragma unroll
        for (int e = 0; e < 8; ++e) {
            float z = hi ? 0.f : v[e];
            af[g][4][e] = (_Float16)z;
        }
    }

    // attention weights for owned units u = 32w + 8a2 + 4hi + p
    float aw_own[16];
    #pragma unroll
    for (int a2 = 0; a2 < 4; ++a2)
        #pragma unroll
        for (int p = 0; p < 4; ++p)
            aw_own[a2 * 4 + p] = attn_w[32 * w + 8 * a2 + 4 * hi + p];
    const float ab = attn_b[0];

    float hcur[16], cst[16], oacc[16];
    #pragma unroll
    for (int i = 0; i < 16; ++i) { hcur[i] = 0.f; cst[i] = 0.f; oacc[i] = 0.f; }
    float lsum = 0.f;

    f32x16 zero16 = {0,0,0,0,0,0,0,0,0,0,0,0,0,0,0,0};
    const int xrow = m * XP;
    const int swz  = m & 15;                    // chunk XOR swizzle
    __syncthreads();

    // ---- initial B fragments from hb[0] (zeros) + x(0) ----
    f16x8 bf[5];
    #pragma unroll
    for (int kt = 0; kt < 4; ++kt) {
        f16x4 lo = *(const f16x4*)&hb[0][m * 64 + ((4 * kt + 2 * hi)     ^ swz) * 4];
        f16x4 hh = *(const f16x4*)&hb[0][m * 64 + ((4 * kt + 2 * hi + 1) ^ swz) * 4];
        bf[kt] = f16x8{lo[0], lo[1], lo[2], lo[3], hh[0], hh[1], hh[2], hh[3]};
    }
    {
        #pragma unroll
        for (int e = 0; e < 8; ++e) bf[4][e] = (_Float16)0.f;
        if (!hi) {
            #pragma unroll
            for (int e = 0; e < 5; ++e) bf[4][e] = xs[xrow + e];
            bf[4][5] = (_Float16)1.f;
        }
    }

    #pragma unroll 1
    for (int t = 0; t < Tc; ++t) {
        // ---- gates: 4 gate tiles x 5 k-tiles ----
        f32x16 acc[4];
        #pragma unroll
        for (int g = 0; g < 4; ++g) {
            acc[g] = __builtin_amdgcn_mfma_f32_32x32x16_f16(af[g][0], bf[0], zero16, 0, 0, 0);
            #pragma unroll
            for (int kt = 1; kt < 5; ++kt)
                acc[g] = __builtin_amdgcn_mfma_f32_32x32x16_f16(af[g][kt], bf[kt], acc[g], 0, 0, 0);
        }
        // ---- cell update: 16 owned (unit,seq m) quads, lane-local ----
        float attnp = 0.f;
        #pragma unroll
        for (int r = 0; r < 16; ++r) {
            float ig = sigm(acc[0][r]);
            float fg = sigm(acc[1][r]);
            float gg = tanh_fast(acc[2][r]);
            float og = sigm(acc[3][r]);
            float cn = fmaf(fg, cst[r], ig * gg);
            cst[r]  = cn;
            float hv = og * tanh_fast(cn);
            hcur[r] = hv;
            attnp = fmaf(hv, aw_own[r], attnp);
        }
        // ---- publish h (fp16, swizzled chunks) + attention partial ----
        _Float16* hw = &hb[(t + 1) & 1][0];
        #pragma unroll
        for (int a2 = 0; a2 < 4; ++a2) {
            f16x4 pk = {(_Float16)hcur[4 * a2 + 0], (_Float16)hcur[4 * a2 + 1],
                        (_Float16)hcur[4 * a2 + 2], (_Float16)hcur[4 * a2 + 3]};
            *(f16x4*)&hw[m * 64 + ((8 * w + 2 * a2 + hi) ^ swz) * 4] = pk;
        }
        attnp += __shfl_xor(attnp, 32);
        if (!hi) ap[w][m] = attnp;
        __syncthreads();
        // ---- score + online accumulation (both waves identical) ----
        float sc = tanh_fast(ap[0][m] + ap[1][m] + ab);
        float ew = __expf(sc);
        lsum += ew;
        #pragma unroll
        for (int i = 0; i < 16; ++i) oacc[i] = fmaf(ew, hcur[i], oacc[i]);
        // ---- build next B fragments ----
        if (t != Tc - 1) {
            const _Float16* hr = &hb[(t + 1) & 1][0];
            #pragma unroll
            for (int kt = 0; kt < 4; ++kt) {
                f16x4 lo = *(const f16x4*)&hr[m * 64 + ((4 * kt + 2 * hi)     ^ swz) * 4];
                f16x4 hh = *(const f16x4*)&hr[m * 64 + ((4 * kt + 2 * hi + 1) ^ swz) * 4];
                bf[kt] = f16x8{lo[0], lo[1], lo[2], lo[3], hh[0], hh[1], hh[2], hh[3]};
            }
            if (!hi) {
                #pragma unroll
                for (int e = 0; e < 5; ++e) bf[4][e] = xs[xrow + (t + 1) * Fc + e];
                bf[4][5] = (_Float16)1.f;
            }
        }
    }

    // ---- epilogue: es[m][u] = oacc/lsum, then E16 + ET ----
    __syncthreads();                    // xs reads done before aliasing
    const float li = fast_rcp(lsum);
    #pragma unroll
    for (int r = 0; r < 16; ++r) {
        int u = 32 * w + 8 * (r >> 2) + 4 * hi + (r & 3);
        es[m * 65 + u] = oacc[r] * li;
    }
    __syncthreads();

    uint* E16u = (uint*)E16 + (size_t)blockIdx.x * 32 * 32;
    for (int idx = tid; idx < 32 * 32; idx += 128) {
        int mm = idx >> 5, hp = idx & 31;
        union { _Float16 h2[2]; uint u; } cv;
        cv.h2[0] = (_Float16)es[mm * 65 + 2 * hp];
        cv.h2[1] = (_Float16)es[mm * 65 + 2 * hp + 1];
        E16u[idx] = cv.u;
    }
    const int bb_ = blockIdx.x >> 5, n0d = (blockIdx.x & 31) * 16;
    uint* ETu = (uint*)ET;
    for (int idx = tid; idx < 64 * 16; idx += 128) {
        int h = idx >> 4, c = idx & 15;
        union { _Float16 h2[2]; uint u; } cv;
        cv.h2[0] = (_Float16)es[(2 * c) * 65 + h];
        cv.h2[1] = (_Float16)es[(2 * c + 1) * 65 + h];
        ETu[((size_t)bb_ * 64 + h) * 512 + n0d + c] = cv.u;
    }
}

// ---------------- Kernel 2: edge coefficients (packed) + degree -------------
__global__ __launch_bounds__(256) void coefq_kernel(
    const float* __restrict__ A,     // [N, N, R]
    const float* __restrict__ gnn_w, // [R]
    const float* __restrict__ gnn_b, // [1]
    float* __restrict__ coefQ,       // [N/4][N][4]
    float* __restrict__ deg)         // [N], pre-zeroed
{
    __shared__ float ct[64 * 68];
    const int t = threadIdx.x;
    const int it = blockIdx.x >> 4, jt = blockIdx.x & 15;
    const int i_loc = t >> 2, chunk = t & 3;
    float gw[5];
    #pragma unroll
    for (int f = 0; f < 5; ++f) gw[f] = gnn_w[f];
    const float gb = gnn_b[0];

    const float* Ab = A + ((size_t)(it * 64 + i_loc) * 1024 + jt * 64 + chunk * 16) * 5;
    float buf[80];
    #pragma unroll
    for (int k = 0; k < 20; ++k)
        *(float4*)&buf[4 * k] = ((const float4*)Ab)[k];

    float cnt = 0.f;
    #pragma unroll
    for (int jj = 0; jj < 16; ++jj) {
        float s = 0.f, d = gb;
        #pragma unroll
        for (int f = 0; f < 5; ++f) { float vv = buf[5 * jj + f]; s += vv; d = fmaf(vv, gw[f], d); }
        float cf = (s > 0.f) ? (d >= 0.f ? d : 0.2f * d) : 0.f;
        ct[i_loc * 68 + chunk * 16 + jj] = cf;
        cnt += (s > 0.f) ? 1.f : 0.f;
    }
    cnt += __shfl_xor(cnt, 1);
    cnt += __shfl_xor(cnt, 2);
    if ((t & 3) == 0) atomicAdd(&deg[it * 64 + i_loc], cnt);
    __syncthreads();

    const int i_o = t & 63;
    #pragma unroll
    for (int p = 0; p < 4; ++p) {
        int jg = (t >> 6) + 4 * p;
        float4 v = *(const float4*)&ct[i_o * 68 + 4 * jg];
        ((float4*)coefQ)[(size_t)(jt * 16 + jg) * 1024 + it * 64 + i_o] = v;
    }
}

// ---------------- Kernel 3: MFMA GNN message pass + prediction head ---------
__global__ __launch_bounds__(256, 2) void gnn_pred_kernel(
    const _Float16* __restrict__ E16,  // [B*N, H]
    const _Float16* __restrict__ ET,   // [B][H][N]
    const float* __restrict__ coefQ,   // [N/4][N][4]
    const float* __restrict__ deg,     // [N]
    const float* __restrict__ pred_w,  // [2H]
    const float* __restrict__ pred_b,  // [1]
    float* __restrict__ preds)         // [B*N], pre-zeroed
{
    __shared__ __align__(16) _Float16 tiles[2][4][64 * 64];  // 64 KB exactly
    const int tid  = threadIdx.x;
    const int w    = tid >> 6;
    const int lane = tid & 63;
    const int l31  = lane & 31;
    const int hi   = lane >> 5;
    const int b    = blockIdx.x >> 4;
    const int it   = blockIdx.x & 15;

    _Float16* EA = &tiles[0][w][0];
    _Float16* EB = &tiles[1][w][0];
    const float4* coefQ4 = (const float4*)coefQ;

    f16x8 eb[2][4];
    #pragma unroll
    for (int ni = 0; ni < 2; ++ni)
        #pragma unroll
        for (int kt = 0; kt < 4; ++kt)
            eb[ni][kt] = *(const f16x8*)(E16 +
                ((size_t)(b * 1024 + it * 64 + ni * 32 + l31) * 64 + 16 * kt + 8 * hi));

    f32x16 zero16 = {0,0,0,0,0,0,0,0,0,0,0,0,0,0,0,0};
    f32x16 oacc[2][2];
    #pragma unroll
    for (int mi = 0; mi < 2; ++mi)
        #pragma unroll
        for (int nh = 0; nh < 2; ++nh) oacc[mi][nh] = zero16;

    #pragma unroll 1
    for (int s = 0; s < 4; ++s) {
        const int jt = w * 4 + s;
        const _Float16* srcA = E16 + (size_t)(b * 1024 + jt * 64) * 64;
        const _Float16* srcB = ET + (size_t)b * 64 * 1024 + jt * 64;
        #pragma unroll
        for (int q = 0; q < 8; ++q) {
            int f = q * 64 + lane, r = f >> 3, c = f & 7;
            uint4 va = *(const uint4*)(srcA + r * 64 + c * 8);
            *(uint4*)(EA + r * 64 + ((c ^ (r & 7)) * 8)) = va;
            uint4 vb = *(const uint4*)(srcB + r * 1024 + c * 8);
            *(uint4*)(EB + r * 64 + ((c ^ (r & 7)) * 8)) = vb;
        }
        f16x8 af[2][4];
        #pragma unroll
        for (int mj = 0; mj < 2; ++mj)
            #pragma unroll
            for (int kt = 0; kt < 4; ++kt)
                af[mj][kt] = *(const f16x8*)(EA + (mj * 32 + l31) * 64 +
                                             (((2 * kt + hi) ^ (l31 & 7)) * 8));
        f32x16 sacc[2][2];
        #pragma unroll
        for (int mj = 0; mj < 2; ++mj)
            #pragma unroll
            for (int ni = 0; ni < 2; ++ni) {
                f32x16 a = __builtin_amdgcn_mfma_f32_32x32x16_f16(af[mj][0], eb[ni][0], zero16, 0, 0, 0);
                #pragma unroll
                for (int kt = 1; kt < 4; ++kt)
                    a = __builtin_amdgcn_mfma_f32_32x32x16_f16(af[mj][kt], eb[ni][kt], a, 0, 0, 0);
                sacc[mj][ni] = a;
            }
        float p[2][2][16];
        #pragma unroll
        for (int mj = 0; mj < 2; ++mj)
            #pragma unroll
            for (int ni = 0; ni < 2; ++ni)
                #pragma unroll
                for (int rg = 0; rg < 4; ++rg) {
                    int j0 = jt * 64 + mj * 32 + 8 * rg + 4 * hi;
                    float4 cf = coefQ4[(size_t)(j0 >> 2) * 1024 + it * 64 + ni * 32 + l31];
                    p[mj][ni][4 * rg + 0] = sacc[mj][ni][4 * rg + 0] * cf.x;
                    p[mj][ni][4 * rg + 1] = sacc[mj][ni][4 * rg + 1] * cf.y;
                    p[mj][ni][4 * rg + 2] = sacc[mj][ni][4 * rg + 2] * cf.z;
                    p[mj][ni][4 * rg + 3] = sacc[mj][ni][4 * rg + 3] * cf.w;
                }
        f16x8 pa[2][4];
        #pragma unroll
        for (int mi = 0; mi < 2; ++mi)
            #pragma unroll
            for (int ktj = 0; ktj < 4; ++ktj) {
                const int mj = ktj >> 1, rg = 2 * (ktj & 1);
                f16x8 fr;
                #pragma unroll
                for (int c4 = 0; c4 < 4; ++c4) {
                    float own_lo = p[mj][mi][rg * 4 + c4];
                    float own_hi = p[mj][mi][(rg + 1) * 4 + c4];
                    float send = hi ? own_lo : own_hi;
                    float recv = __shfl_xor(send, 32);
                    float lo = hi ? recv : own_lo;
                    float hv = hi ? own_hi : recv;
                    fr[c4]     = (_Float16)lo;
                    fr[4 + c4] = (_Float16)hv;
                }
                pa[mi][ktj] = fr;
            }
        f16x8 bb[2][4];
        #pragma unroll
        for (int nh = 0; nh < 2; ++nh)
            #pragma unroll
            for (int ktj = 0; ktj < 4; ++ktj)
                bb[nh][ktj] = *(const f16x8*)(EB + (nh * 32 + l31) * 64 +
                                              (((2 * ktj + hi) ^ (l31 & 7)) * 8));
        #pragma unroll
        for (int mi = 0; mi < 2; ++mi)
            #pragma unroll
            for (int nh = 0; nh < 2; ++nh)
                #pragma unroll
                for (int ktj = 0; ktj < 4; ++ktj)
                    oacc[mi][nh] = __builtin_amdgcn_mfma_f32_32x32x16_f16(
                        pa[mi][ktj], bb[nh][ktj], oacc[mi][nh], 0, 0, 0);
    }

    const float pwh0 = pred_w[64 + l31];
    const float pwh1 = pred_w[96 + l31];
    #pragma unroll
    for (int mi = 0; mi < 2; ++mi)
        #pragma unroll
        for (int r = 0; r < 16; ++r) {
            float v = oacc[mi][0][r] * pwh0 + oacc[mi][1][r] * pwh1;
            v += __shfl_xor(v, 1);  v += __shfl_xor(v, 2);  v += __shfl_xor(v, 4);
            v += __shfl_xor(v, 8);  v += __shfl_xor(v, 16);
            int i_loc = mi * 32 + 8 * (r >> 2) + (r & 3) + 4 * hi;
            int gi = it * 64 + i_loc;
            if (l31 == 0) {
                float dg = deg[gi];
                atomicAdd(&preds[b * 1024 + gi], v * fast_rcp(dg));
            }
        }
    if (w == 0) {
        const float pb0 = pred_b[0];
        #pragma unroll
        for (int ni = 0; ni < 2; ++ni) {
            float dot = 0.f;
            #pragma unroll
            for (int kt = 0; kt < 4; ++kt)
                #pragma unroll
                for (int e = 0; e < 8; ++e)
                    dot = fmaf((float)eb[ni][kt][e], pred_w[16 * kt + 8 * hi + e], dot);
            dot += __shfl_xor(dot, 32);
            if (hi == 0)
                atomicAdd(&preds[b * 1024 + it * 64 + ni * 32 + l31], dot + pb0);
        }
    }
}

extern "C" void kernel_launch(void* const* d_in, const int* in_sizes, int n_in,
                              void* d_out, int out_size, void* d_ws, size_t ws_size,
                              hipStream_t stream) {
    const float* x      = (const float*)d_in[0];
    const float* A      = (const float*)d_in[1];
    const float* Wih    = (const float*)d_in[2];
    const float* Whh    = (const float*)d_in[3];
    const float* bih    = (const float*)d_in[4];
    const float* bhh    = (const float*)d_in[5];
    const float* attn_w = (const float*)d_in[6];
    const float* attn_b = (const float*)d_in[7];
    const float* gnn_w  = (const float*)d_in[8];
    const float* gnn_b  = (const float*)d_in[9];
    const float* pred_w = (const float*)d_in[10];
    const float* pred_b = (const float*)d_in[11];
    float* preds = (float*)d_out;

    // ws: E16 (4MB) | ET (4MB) | coefQ (4MB) | deg (4KB)
    _Float16* E16 = (_Float16*)d_ws;
    _Float16* ET  = E16 + (size_t)BNc * Hc;
    float* coefQ  = (float*)(ET + (size_t)BNc * Hc);
    float* deg    = coefQ + (size_t)Nc * Nc;

    hipMemsetAsync(preds, 0, (size_t)out_size * sizeof(float), stream);
    hipMemsetAsync(deg, 0, Nc * sizeof(float), stream);

    lstm_attn_kernel<<<BNc / 32, 128, 0, stream>>>(x, Wih, Whh, bih, bhh,
                                                   attn_w, attn_b, E16, ET);
    coefq_kernel<<<256, 256, 0, stream>>>(A, gnn_w, gnn_b, coefQ, deg);
    gnn_pred_kernel<<<Bc * (Nc / 64), 256, 0, stream>>>(E16, ET, coefQ, deg,
                                                        pred_w, pred_b, preds);
}

// Round 5
// 239.731 us; speedup vs baseline: 1.1497x; 1.1497x over previous
//
#include <hip/hip_runtime.h>

// Problem constants (B,N,T,F,H,R) = (32,1024,32,5,64,5)
constexpr int Bc = 32, Nc = 1024, Tc = 32, Fc = 5, Hc = 64;
constexpr int BNc = Bc * Nc;   // 32768 sequences

#define DEVFN __device__ __forceinline__

typedef _Float16 f16x8 __attribute__((ext_vector_type(8)));
typedef _Float16 f16x4 __attribute__((ext_vector_type(4)));
typedef float    f32x16 __attribute__((ext_vector_type(16)));

DEVFN float fast_rcp(float x) { return __builtin_amdgcn_rcpf(x); }
DEVFN float tanh_fast(float x) { return 1.f - 2.f * fast_rcp(__expf(2.f * x) + 1.f); }

// ---------------- Kernel 1: fused LSTM + temporal attention (MFMA) ----------
// Block = 128 thr (2 waves) x 32 seqs; wave w owns hidden units [32w, 32w+32).
// Cell update uses fused-denominator algebra: 5 exp + 2 rcp per unit (vs 10
// trans naive) — the trans pipe (quarter-rate) is the measured bottleneck.
//   c' = (c*t1 + z*v) / (t1*v),  t1=(1+e^-i)(e^2g+1), v=1+e^-f, z=e^2g-1
//   h  = (e^2c'-1) / ((e^2c'+1)(1+e^-o))
__global__ __launch_bounds__(128, 2) void lstm_attn_kernel(
    const float* __restrict__ x,      // [BN, T, F]
    const float* __restrict__ Wih,    // [4H, F]
    const float* __restrict__ Whh,    // [4H, H]
    const float* __restrict__ bih,    // [4H]
    const float* __restrict__ bhh,    // [4H]
    const float* __restrict__ attn_w, // [H]
    const float* __restrict__ attn_b, // [1]
    _Float16* __restrict__ E16,       // [B*N, H] fp16 row-major
    _Float16* __restrict__ ET)        // [B][H][N] fp16 transposed
{
    constexpr int XP = 164;                     // x pitch (halves)
    __shared__ __align__(16) _Float16 xs[32 * XP];   // 10.5 KB; aliased w/ es
    __shared__ __align__(16) _Float16 hb[2][32 * 64];// 8 KB h exchange
    __shared__ float ap[2][32];                 // attn partials per wave
    float* es = (float*)xs;                     // [32][65] epilogue bounce

    const int tid  = threadIdx.x;
    const int w    = tid >> 6;                  // wave id (0,1)
    const int lane = tid & 63;
    const int m    = lane & 31;                 // seq column
    const int hi   = lane >> 5;

    // ---- stage x (fp32 -> fp16 LDS) ----
    const float* xg = x + (size_t)blockIdx.x * 32 * Tc * Fc;
    for (int i = tid; i < 32 * 160; i += 128) {
        int mm = i / 160, o = i - mm * 160;
        xs[mm * XP + o] = (_Float16)xg[i];
    }
    // zero h buffer 0
    for (int i = tid; i < 1024; i += 128) ((uint*)&hb[0][0])[i] = 0u;

    // ---- preload A fragments: af[g][kt], jt = 2g+w, row j = 32*jt + m ----
    f16x8 af[4][5];
    #pragma unroll
    for (int g = 0; g < 4; ++g) {
        const int j = 32 * (2 * g + w) + m;     // = 64g + 32w + m
        #pragma unroll
        for (int kt = 0; kt < 4; ++kt) {
            const float* wp = Whh + j * 64 + kt * 16 + 8 * hi;
            float4 u0 = *(const float4*)wp;
            float4 u1 = *(const float4*)(wp + 4);
            af[g][kt] = f16x8{(_Float16)u0.x, (_Float16)u0.y, (_Float16)u0.z, (_Float16)u0.w,
                              (_Float16)u1.x, (_Float16)u1.y, (_Float16)u1.z, (_Float16)u1.w};
        }
        float v[8];
        #pragma unroll
        for (int e = 0; e < 5; ++e) v[e] = Wih[j * Fc + e];
        v[5] = bih[j] + bhh[j]; v[6] = 0.f; v[7] = 0.f;
        #pragma unroll
        for (int e = 0; e < 8; ++e) {
            float z = hi ? 0.f : v[e];
            af[g][4][e] = (_Float16)z;
        }
    }

    // attention weights for owned units u = 32w + 8a2 + 4hi + p
    float aw_own[16];
    #pragma unroll
    for (int a2 = 0; a2 < 4; ++a2)
        #pragma unroll
        for (int p = 0; p < 4; ++p)
            aw_own[a2 * 4 + p] = attn_w[32 * w + 8 * a2 + 4 * hi + p];
    const float ab = attn_b[0];

    float hcur[16], cst[16], oacc[16];
    #pragma unroll
    for (int i = 0; i < 16; ++i) { hcur[i] = 0.f; cst[i] = 0.f; oacc[i] = 0.f; }
    float lsum = 0.f;

    f32x16 zero16 = {0,0,0,0,0,0,0,0,0,0,0,0,0,0,0,0};
    const int xrow = m * XP;
    const int swz  = m & 15;                    // chunk XOR swizzle
    __syncthreads();

    // ---- initial B fragments from hb[0] (zeros) + x(0) ----
    f16x8 bf[5];
    #pragma unroll
    for (int kt = 0; kt < 4; ++kt) {
        f16x4 lo = *(const f16x4*)&hb[0][m * 64 + ((4 * kt + 2 * hi)     ^ swz) * 4];
        f16x4 hh = *(const f16x4*)&hb[0][m * 64 + ((4 * kt + 2 * hi + 1) ^ swz) * 4];
        bf[kt] = f16x8{lo[0], lo[1], lo[2], lo[3], hh[0], hh[1], hh[2], hh[3]};
    }
    {
        #pragma unroll
        for (int e = 0; e < 8; ++e) bf[4][e] = (_Float16)0.f;
        if (!hi) {
            #pragma unroll
            for (int e = 0; e < 5; ++e) bf[4][e] = xs[xrow + e];
            bf[4][5] = (_Float16)1.f;
        }
    }

    #pragma unroll 1
    for (int t = 0; t < Tc; ++t) {
        // ---- gates: 4 gate tiles x 5 k-tiles ----
        f32x16 acc[4];
        #pragma unroll
        for (int g = 0; g < 4; ++g) {
            acc[g] = __builtin_amdgcn_mfma_f32_32x32x16_f16(af[g][0], bf[0], zero16, 0, 0, 0);
            #pragma unroll
            for (int kt = 1; kt < 5; ++kt)
                acc[g] = __builtin_amdgcn_mfma_f32_32x32x16_f16(af[g][kt], bf[kt], acc[g], 0, 0, 0);
        }
        // ---- cell update: fused-denominator form, 5 exp + 2 rcp per unit ----
        float attnp = 0.f;
        #pragma unroll
        for (int r = 0; r < 16; ++r) {
            float ei = __expf(-acc[0][r]);          // e^{-i}
            float ef = __expf(-acc[1][r]);          // e^{-f}
            float Eg = __expf(2.f * acc[2][r]);     // e^{2g}
            float eo = __expf(-acc[3][r]);          // e^{-o}
            float u  = 1.f + ei;
            float v  = 1.f + ef;
            float wq = Eg + 1.f;
            float z  = Eg - 1.f;
            float t1 = u * wq;
            float num = fmaf(cst[r], t1, z * v);
            float cn = num * fast_rcp(t1 * v);
            cst[r] = cn;
            float E2 = __expf(2.f * cn);
            float hv = (E2 - 1.f) * fast_rcp((E2 + 1.f) * (1.f + eo));
            hcur[r] = hv;
            attnp = fmaf(hv, aw_own[r], attnp);
        }
        // ---- publish h (fp16, swizzled chunks) + attention partial ----
        _Float16* hw = &hb[(t + 1) & 1][0];
        #pragma unroll
        for (int a2 = 0; a2 < 4; ++a2) {
            f16x4 pk = {(_Float16)hcur[4 * a2 + 0], (_Float16)hcur[4 * a2 + 1],
                        (_Float16)hcur[4 * a2 + 2], (_Float16)hcur[4 * a2 + 3]};
            *(f16x4*)&hw[m * 64 + ((8 * w + 2 * a2 + hi) ^ swz) * 4] = pk;
        }
        attnp += __shfl_xor(attnp, 32);
        if (!hi) ap[w][m] = attnp;
        __syncthreads();
        // ---- score + online accumulation (both waves identical) ----
        float sc = tanh_fast(ap[0][m] + ap[1][m] + ab);
        float ew = __expf(sc);
        lsum += ew;
        #pragma unroll
        for (int i = 0; i < 16; ++i) oacc[i] = fmaf(ew, hcur[i], oacc[i]);
        // ---- build next B fragments ----
        if (t != Tc - 1) {
            const _Float16* hr = &hb[(t + 1) & 1][0];
            #pragma unroll
            for (int kt = 0; kt < 4; ++kt) {
                f16x4 lo = *(const f16x4*)&hr[m * 64 + ((4 * kt + 2 * hi)     ^ swz) * 4];
                f16x4 hh = *(const f16x4*)&hr[m * 64 + ((4 * kt + 2 * hi + 1) ^ swz) * 4];
                bf[kt] = f16x8{lo[0], lo[1], lo[2], lo[3], hh[0], hh[1], hh[2], hh[3]};
            }
            if (!hi) {
                #pragma unroll
                for (int e = 0; e < 5; ++e) bf[4][e] = xs[xrow + (t + 1) * Fc + e];
                bf[4][5] = (_Float16)1.f;
            }
        }
    }

    // ---- epilogue: es[m][u] = oacc/lsum, then E16 + ET ----
    __syncthreads();                    // xs reads done before aliasing
    const float li = fast_rcp(lsum);
    #pragma unroll
    for (int r = 0; r < 16; ++r) {
        int u = 32 * w + 8 * (r >> 2) + 4 * hi + (r & 3);
        es[m * 65 + u] = oacc[r] * li;
    }
    __syncthreads();

    uint* E16u = (uint*)E16 + (size_t)blockIdx.x * 32 * 32;
    for (int idx = tid; idx < 32 * 32; idx += 128) {
        int mm = idx >> 5, hp = idx & 31;
        union { _Float16 h2[2]; uint u; } cv;
        cv.h2[0] = (_Float16)es[mm * 65 + 2 * hp];
        cv.h2[1] = (_Float16)es[mm * 65 + 2 * hp + 1];
        E16u[idx] = cv.u;
    }
    const int bb_ = blockIdx.x >> 5, n0d = (blockIdx.x & 31) * 16;
    uint* ETu = (uint*)ET;
    for (int idx = tid; idx < 64 * 16; idx += 128) {
        int h = idx >> 4, c = idx & 15;
        union { _Float16 h2[2]; uint u; } cv;
        cv.h2[0] = (_Float16)es[(2 * c) * 65 + h];
        cv.h2[1] = (_Float16)es[(2 * c + 1) * 65 + h];
        ETu[((size_t)bb_ * 64 + h) * 512 + n0d + c] = cv.u;
    }
}

// ---------------- Kernel 2: edge coefficients (packed) + degree -------------
__global__ __launch_bounds__(256) void coefq_kernel(
    const float* __restrict__ A,     // [N, N, R]
    const float* __restrict__ gnn_w, // [R]
    const float* __restrict__ gnn_b, // [1]
    float* __restrict__ coefQ,       // [N/4][N][4]
    float* __restrict__ deg)         // [N], pre-zeroed
{
    __shared__ float ct[64 * 68];
    const int t = threadIdx.x;
    const int it = blockIdx.x >> 4, jt = blockIdx.x & 15;
    const int i_loc = t >> 2, chunk = t & 3;
    float gw[5];
    #pragma unroll
    for (int f = 0; f < 5; ++f) gw[f] = gnn_w[f];
    const float gb = gnn_b[0];

    const float* Ab = A + ((size_t)(it * 64 + i_loc) * 1024 + jt * 64 + chunk * 16) * 5;
    float buf[80];
    #pragma unroll
    for (int k = 0; k < 20; ++k)
        *(float4*)&buf[4 * k] = ((const float4*)Ab)[k];

    float cnt = 0.f;
    #pragma unroll
    for (int jj = 0; jj < 16; ++jj) {
        float s = 0.f, d = gb;
        #pragma unroll
        for (int f = 0; f < 5; ++f) { float vv = buf[5 * jj + f]; s += vv; d = fmaf(vv, gw[f], d); }
        float cf = (s > 0.f) ? (d >= 0.f ? d : 0.2f * d) : 0.f;
        ct[i_loc * 68 + chunk * 16 + jj] = cf;
        cnt += (s > 0.f) ? 1.f : 0.f;
    }
    cnt += __shfl_xor(cnt, 1);
    cnt += __shfl_xor(cnt, 2);
    if ((t & 3) == 0) atomicAdd(&deg[it * 64 + i_loc], cnt);
    __syncthreads();

    const int i_o = t & 63;
    #pragma unroll
    for (int p = 0; p < 4; ++p) {
        int jg = (t >> 6) + 4 * p;
        float4 v = *(const float4*)&ct[i_o * 68 + 4 * jg];
        ((float4*)coefQ)[(size_t)(jt * 16 + jg) * 1024 + it * 64 + i_o] = v;
    }
}

// ---------------- Kernel 3: MFMA GNN message pass + prediction head ---------
// De-spilled: per (mj,mi) fuse S'-chain -> coef-mul -> fp16 pack -> O-MFMA so
// only one 16-reg S accumulator is live at a time (was sacc64+p64 -> scratch).
__global__ __launch_bounds__(256, 2) void gnn_pred_kernel(
    const _Float16* __restrict__ E16,  // [B*N, H]
    const _Float16* __restrict__ ET,   // [B][H][N]
    const float* __restrict__ coefQ,   // [N/4][N][4]
    const float* __restrict__ deg,     // [N]
    const float* __restrict__ pred_w,  // [2H]
    const float* __restrict__ pred_b,  // [1]
    float* __restrict__ preds)         // [B*N], pre-zeroed
{
    __shared__ __align__(16) _Float16 tiles[2][4][64 * 64];  // 64 KB exactly
    const int tid  = threadIdx.x;
    const int w    = tid >> 6;
    const int lane = tid & 63;
    const int l31  = lane & 31;
    const int hi   = lane >> 5;
    const int b    = blockIdx.x >> 4;
    const int it   = blockIdx.x & 15;

    _Float16* EA = &tiles[0][w][0];
    _Float16* EB = &tiles[1][w][0];
    const float4* coefQ4 = (const float4*)coefQ;

    f16x8 eb[2][4];
    #pragma unroll
    for (int ni = 0; ni < 2; ++ni)
        #pragma unroll
        for (int kt = 0; kt < 4; ++kt)
            eb[ni][kt] = *(const f16x8*)(E16 +
                ((size_t)(b * 1024 + it * 64 + ni * 32 + l31) * 64 + 16 * kt + 8 * hi));

    f32x16 zero16 = {0,0,0,0,0,0,0,0,0,0,0,0,0,0,0,0};
    f32x16 oacc[2][2];
    #pragma unroll
    for (int mi = 0; mi < 2; ++mi)
        #pragma unroll
        for (int nh = 0; nh < 2; ++nh) oacc[mi][nh] = zero16;

    #pragma unroll 1
    for (int s = 0; s < 4; ++s) {
        const int jt = w * 4 + s;
        const _Float16* srcA = E16 + (size_t)(b * 1024 + jt * 64) * 64;
        const _Float16* srcB = ET + (size_t)b * 64 * 1024 + jt * 64;
        #pragma unroll
        for (int q = 0; q < 8; ++q) {
            int f = q * 64 + lane, r = f >> 3, c = f & 7;
            uint4 va = *(const uint4*)(srcA + r * 64 + c * 8);
            *(uint4*)(EA + r * 64 + ((c ^ (r & 7)) * 8)) = va;
            uint4 vb = *(const uint4*)(srcB + r * 1024 + c * 8);
            *(uint4*)(EB + r * 64 + ((c ^ (r & 7)) * 8)) = vb;
        }
        #pragma unroll 1
        for (int mj = 0; mj < 2; ++mj) {
            // A-frags of Ej for this 32-row half
            f16x8 af[4];
            #pragma unroll
            for (int kt = 0; kt < 4; ++kt)
                af[kt] = *(const f16x8*)(EA + (mj * 32 + l31) * 64 +
                                         (((2 * kt + hi) ^ (l31 & 7)) * 8));
            #pragma unroll
            for (int mi = 0; mi < 2; ++mi) {
                // S' = Ej . Ei^T  (16 regs live)
                f32x16 a = __builtin_amdgcn_mfma_f32_32x32x16_f16(af[0], eb[mi][0], zero16, 0, 0, 0);
                #pragma unroll
                for (int kt = 1; kt < 4; ++kt)
                    a = __builtin_amdgcn_mfma_f32_32x32x16_f16(af[kt], eb[mi][kt], a, 0, 0, 0);
                // P = S' * coef, in place
                #pragma unroll
                for (int rg = 0; rg < 4; ++rg) {
                    int j0 = jt * 64 + mj * 32 + 8 * rg + 4 * hi;
                    float4 cf = coefQ4[(size_t)(j0 >> 2) * 1024 + it * 64 + mi * 32 + l31];
                    a[4 * rg + 0] *= cf.x; a[4 * rg + 1] *= cf.y;
                    a[4 * rg + 2] *= cf.z; a[4 * rg + 3] *= cf.w;
                }
                // pack to A-layout fp16 frags (kk = local K-tile), lane^32 swap
                f16x8 pa[2];
                #pragma unroll
                for (int kk = 0; kk < 2; ++kk) {
                    const int rg = 2 * kk;
                    #pragma unroll
                    for (int c4 = 0; c4 < 4; ++c4) {
                        float own_lo = a[rg * 4 + c4];
                        float own_hi = a[(rg + 1) * 4 + c4];
                        float send = hi ? own_lo : own_hi;
                        float recv = __shfl_xor(send, 32);
                        float lo = hi ? recv : own_lo;
                        float hv = hi ? own_hi : recv;
                        pa[kk][c4]     = (_Float16)lo;
                        pa[kk][4 + c4] = (_Float16)hv;
                    }
                }
                // O += P . Ej  (ktj = 2*mj + kk), bb re-read from LDS per use
                #pragma unroll
                for (int nh = 0; nh < 2; ++nh)
                    #pragma unroll
                    for (int kk = 0; kk < 2; ++kk) {
                        const int ktj = 2 * mj + kk;
                        f16x8 bb = *(const f16x8*)(EB + (nh * 32 + l31) * 64 +
                                                   (((2 * ktj + hi) ^ (l31 & 7)) * 8));
                        oacc[mi][nh] = __builtin_amdgcn_mfma_f32_32x32x16_f16(
                            pa[kk], bb, oacc[mi][nh], 0, 0, 0);
                    }
            }
        }
    }

    const float pwh0 = pred_w[64 + l31];
    const float pwh1 = pred_w[96 + l31];
    #pragma unroll
    for (int mi = 0; mi < 2; ++mi)
        #pragma unroll
        for (int r = 0; r < 16; ++r) {
            float v = oacc[mi][0][r] * pwh0 + oacc[mi][1][r] * pwh1;
            v += __shfl_xor(v, 1);  v += __shfl_xor(v, 2);  v += __shfl_xor(v, 4);
            v += __shfl_xor(v, 8);  v += __shfl_xor(v, 16);
            int i_loc = mi * 32 + 8 * (r >> 2) + (r & 3) + 4 * hi;
            int gi = it * 64 + i_loc;
            if (l31 == 0) {
                float dg = deg[gi];
                atomicAdd(&preds[b * 1024 + gi], v * fast_rcp(dg));
            }
        }
    if (w == 0) {
        const float pb0 = pred_b[0];
        #pragma unroll
        for (int ni = 0; ni < 2; ++ni) {
            float dot = 0.f;
            #pragma unroll
            for (int kt = 0; kt < 4; ++kt)
                #pragma unroll
                for (int e = 0; e < 8; ++e)
                    dot = fmaf((float)eb[ni][kt][e], pred_w[16 * kt + 8 * hi + e], dot);
            dot += __shfl_xor(dot, 32);
            if (hi == 0)
                atomicAdd(&preds[b * 1024 + it * 64 + ni * 32 + l31], dot + pb0);
        }
    }
}

extern "C" void kernel_launch(void* const* d_in, const int* in_sizes, int n_in,
                              void* d_out, int out_size, void* d_ws, size_t ws_size,
                              hipStream_t stream) {
    const float* x      = (const float*)d_in[0];
    const float* A      = (const float*)d_in[1];
    const float* Wih    = (const float*)d_in[2];
    const float* Whh    = (const float*)d_in[3];
    const float* bih    = (const float*)d_in[4];
    const float* bhh    = (const float*)d_in[5];
    const float* attn_w = (const float*)d_in[6];
    const float* attn_b = (const float*)d_in[7];
    const float* gnn_w  = (const float*)d_in[8];
    const float* gnn_b  = (const float*)d_in[9];
    const float* pred_w = (const float*)d_in[10];
    const float* pred_b = (const float*)d_in[11];
    float* preds = (float*)d_out;

    // ws: E16 (4MB) | ET (4MB) | coefQ (4MB) | deg (4KB)
    _Float16* E16 = (_Float16*)d_ws;
    _Float16* ET  = E16 + (size_t)BNc * Hc;
    float* coefQ  = (float*)(ET + (size_t)BNc * Hc);
    float* deg    = coefQ + (size_t)Nc * Nc;

    hipMemsetAsync(preds, 0, (size_t)out_size * sizeof(float), stream);
    hipMemsetAsync(deg, 0, Nc * sizeof(float), stream);

    lstm_attn_kernel<<<BNc / 32, 128, 0, stream>>>(x, Wih, Whh, bih, bhh,
                                                   attn_w, attn_b, E16, ET);
    coefq_kernel<<<256, 256, 0, stream>>>(A, gnn_w, gnn_b, coefQ, deg);
    gnn_pred_kernel<<<Bc * (Nc / 64), 256, 0, stream>>>(E16, ET, coefQ, deg,
                                                        pred_w, pred_b, preds);
}

// Round 6
// 237.314 us; speedup vs baseline: 1.1614x; 1.0102x over previous
//
#include <hip/hip_runtime.h>

// Problem constants (B,N,T,F,H,R) = (32,1024,32,5,64,5)
constexpr int Bc = 32, Nc = 1024, Tc = 32, Fc = 5, Hc = 64;
constexpr int BNc = Bc * Nc;   // 32768 sequences

#define DEVFN __device__ __forceinline__

typedef _Float16 f16x8 __attribute__((ext_vector_type(8)));
typedef _Float16 f16x4 __attribute__((ext_vector_type(4)));
typedef float    f32x16 __attribute__((ext_vector_type(16)));

DEVFN float fast_rcp(float x) { return __builtin_amdgcn_rcpf(x); }
DEVFN float tanh_fast(float x) { return 1.f - 2.f * fast_rcp(__expf(2.f * x) + 1.f); }

// ---------------- Kernel 1: fused LSTM + temporal attention (MFMA) ----------
// Block = 128 thr (2 waves) x 32 seqs; wave w owns hidden units [32w, 32w+32).
// Cell update: fused-denominator algebra (5 exp + 2 rcp per unit).
// hb pitch = 68 halfs: row base bank = (m*34)%32 spreads rows across banks
// (pitch 64 put all b64 h-reads at even-bank offsets -> 4-way conflicts).
__global__ __launch_bounds__(128, 2) void lstm_attn_kernel(
    const float* __restrict__ x,      // [BN, T, F]
    const float* __restrict__ Wih,    // [4H, F]
    const float* __restrict__ Whh,    // [4H, H]
    const float* __restrict__ bih,    // [4H]
    const float* __restrict__ bhh,    // [4H]
    const float* __restrict__ attn_w, // [H]
    const float* __restrict__ attn_b, // [1]
    _Float16* __restrict__ E16,       // [B*N, H] fp16 row-major
    _Float16* __restrict__ ET)        // [B][H][N] fp16 transposed
{
    constexpr int XP = 164;                     // x pitch (halves)
    constexpr int HP = 68;                      // h-exchange pitch (halves)
    __shared__ __align__(16) _Float16 xs[32 * XP];   // 10.5 KB; aliased w/ es
    __shared__ __align__(16) _Float16 hb[2][32 * HP];// h exchange
    __shared__ float ap[2][32];                 // attn partials per wave
    float* es = (float*)xs;                     // [32][65] epilogue bounce

    const int tid  = threadIdx.x;
    const int w    = tid >> 6;                  // wave id (0,1)
    const int lane = tid & 63;
    const int m    = lane & 31;                 // seq column
    const int hi   = lane >> 5;

    // ---- stage x (fp32 -> fp16 LDS) ----
    const float* xg = x + (size_t)blockIdx.x * 32 * Tc * Fc;
    for (int i = tid; i < 32 * 160; i += 128) {
        int mm = i / 160, o = i - mm * 160;
        xs[mm * XP + o] = (_Float16)xg[i];
    }
    // zero h buffer 0
    for (int i = tid; i < 32 * HP / 2; i += 128) ((uint*)&hb[0][0])[i] = 0u;

    // ---- preload A fragments: af[g][kt], jt = 2g+w, row j = 32*jt + m ----
    f16x8 af[4][5];
    #pragma unroll
    for (int g = 0; g < 4; ++g) {
        const int j = 32 * (2 * g + w) + m;     // = 64g + 32w + m
        #pragma unroll
        for (int kt = 0; kt < 4; ++kt) {
            const float* wp = Whh + j * 64 + kt * 16 + 8 * hi;
            float4 u0 = *(const float4*)wp;
            float4 u1 = *(const float4*)(wp + 4);
            af[g][kt] = f16x8{(_Float16)u0.x, (_Float16)u0.y, (_Float16)u0.z, (_Float16)u0.w,
                              (_Float16)u1.x, (_Float16)u1.y, (_Float16)u1.z, (_Float16)u1.w};
        }
        float v[8];
        #pragma unroll
        for (int e = 0; e < 5; ++e) v[e] = Wih[j * Fc + e];
        v[5] = bih[j] + bhh[j]; v[6] = 0.f; v[7] = 0.f;
        #pragma unroll
        for (int e = 0; e < 8; ++e) {
            float z = hi ? 0.f : v[e];
            af[g][4][e] = (_Float16)z;
        }
    }

    // attention weights for owned units u = 32w + 8a2 + 4hi + p
    float aw_own[16];
    #pragma unroll
    for (int a2 = 0; a2 < 4; ++a2)
        #pragma unroll
        for (int p = 0; p < 4; ++p)
            aw_own[a2 * 4 + p] = attn_w[32 * w + 8 * a2 + 4 * hi + p];
    const float ab = attn_b[0];

    float hcur[16], cst[16], oacc[16];
    #pragma unroll
    for (int i = 0; i < 16; ++i) { hcur[i] = 0.f; cst[i] = 0.f; oacc[i] = 0.f; }
    float lsum = 0.f;

    f32x16 zero16 = {0,0,0,0,0,0,0,0,0,0,0,0,0,0,0,0};
    const int xrow = m * XP;
    const int swz  = m & 15;                    // chunk XOR swizzle
    __syncthreads();

    // ---- initial B fragments from hb[0] (zeros) + x(0) ----
    f16x8 bf[5];
    #pragma unroll
    for (int kt = 0; kt < 4; ++kt) {
        f16x4 lo = *(const f16x4*)&hb[0][m * HP + ((4 * kt + 2 * hi)     ^ swz) * 4];
        f16x4 hh = *(const f16x4*)&hb[0][m * HP + ((4 * kt + 2 * hi + 1) ^ swz) * 4];
        bf[kt] = f16x8{lo[0], lo[1], lo[2], lo[3], hh[0], hh[1], hh[2], hh[3]};
    }
    {
        #pragma unroll
        for (int e = 0; e < 8; ++e) bf[4][e] = (_Float16)0.f;
        if (!hi) {
            #pragma unroll
            for (int e = 0; e < 5; ++e) bf[4][e] = xs[xrow + e];
            bf[4][5] = (_Float16)1.f;
        }
    }

    #pragma unroll 1
    for (int t = 0; t < Tc; ++t) {
        // ---- gates: 4 gate tiles x 5 k-tiles ----
        f32x16 acc[4];
        #pragma unroll
        for (int g = 0; g < 4; ++g) {
            acc[g] = __builtin_amdgcn_mfma_f32_32x32x16_f16(af[g][0], bf[0], zero16, 0, 0, 0);
            #pragma unroll
            for (int kt = 1; kt < 5; ++kt)
                acc[g] = __builtin_amdgcn_mfma_f32_32x32x16_f16(af[g][kt], bf[kt], acc[g], 0, 0, 0);
        }
        // ---- cell update: fused-denominator form, 5 exp + 2 rcp per unit ----
        float attnp = 0.f;
        #pragma unroll
        for (int r = 0; r < 16; ++r) {
            float ei = __expf(-acc[0][r]);          // e^{-i}
            float ef = __expf(-acc[1][r]);          // e^{-f}
            float Eg = __expf(2.f * acc[2][r]);     // e^{2g}
            float eo = __expf(-acc[3][r]);          // e^{-o}
            float u  = 1.f + ei;
            float v  = 1.f + ef;
            float wq = Eg + 1.f;
            float z  = Eg - 1.f;
            float t1 = u * wq;
            float num = fmaf(cst[r], t1, z * v);
            float cn = num * fast_rcp(t1 * v);
            cst[r] = cn;
            float E2 = __expf(2.f * cn);
            float hv = (E2 - 1.f) * fast_rcp((E2 + 1.f) * (1.f + eo));
            hcur[r] = hv;
            attnp = fmaf(hv, aw_own[r], attnp);
        }
        // ---- publish h (fp16, swizzled chunks) + attention partial ----
        _Float16* hw = &hb[(t + 1) & 1][0];
        #pragma unroll
        for (int a2 = 0; a2 < 4; ++a2) {
            f16x4 pk = {(_Float16)hcur[4 * a2 + 0], (_Float16)hcur[4 * a2 + 1],
                        (_Float16)hcur[4 * a2 + 2], (_Float16)hcur[4 * a2 + 3]};
            *(f16x4*)&hw[m * HP + ((8 * w + 2 * a2 + hi) ^ swz) * 4] = pk;
        }
        attnp += __shfl_xor(attnp, 32);
        if (!hi) ap[w][m] = attnp;
        __syncthreads();
        // ---- score + online accumulation (both waves identical) ----
        float sc = tanh_fast(ap[0][m] + ap[1][m] + ab);
        float ew = __expf(sc);
        lsum += ew;
        #pragma unroll
        for (int i = 0; i < 16; ++i) oacc[i] = fmaf(ew, hcur[i], oacc[i]);
        // ---- build next B fragments ----
        if (t != Tc - 1) {
            const _Float16* hr = &hb[(t + 1) & 1][0];
            #pragma unroll
            for (int kt = 0; kt < 4; ++kt) {
                f16x4 lo = *(const f16x4*)&hr[m * HP + ((4 * kt + 2 * hi)     ^ swz) * 4];
                f16x4 hh = *(const f16x4*)&hr[m * HP + ((4 * kt + 2 * hi + 1) ^ swz) * 4];
                bf[kt] = f16x8{lo[0], lo[1], lo[2], lo[3], hh[0], hh[1], hh[2], hh[3]};
            }
            if (!hi) {
                #pragma unroll
                for (int e = 0; e < 5; ++e) bf[4][e] = xs[xrow + (t + 1) * Fc + e];
                bf[4][5] = (_Float16)1.f;
            }
        }
    }

    // ---- epilogue: es[m][u] = oacc/lsum, then E16 + ET ----
    __syncthreads();                    // xs reads done before aliasing
    const float li = fast_rcp(lsum);
    #pragma unroll
    for (int r = 0; r < 16; ++r) {
        int u = 32 * w + 8 * (r >> 2) + 4 * hi + (r & 3);
        es[m * 65 + u] = oacc[r] * li;
    }
    __syncthreads();

    uint* E16u = (uint*)E16 + (size_t)blockIdx.x * 32 * 32;
    for (int idx = tid; idx < 32 * 32; idx += 128) {
        int mm = idx >> 5, hp = idx & 31;
        union { _Float16 h2[2]; uint u; } cv;
        cv.h2[0] = (_Float16)es[mm * 65 + 2 * hp];
        cv.h2[1] = (_Float16)es[mm * 65 + 2 * hp + 1];
        E16u[idx] = cv.u;
    }
    const int bb_ = blockIdx.x >> 5, n0d = (blockIdx.x & 31) * 16;
    uint* ETu = (uint*)ET;
    for (int idx = tid; idx < 64 * 16; idx += 128) {
        int h = idx >> 4, c = idx & 15;
        union { _Float16 h2[2]; uint u; } cv;
        cv.h2[0] = (_Float16)es[(2 * c) * 65 + h];
        cv.h2[1] = (_Float16)es[(2 * c + 1) * 65 + h];
        ETu[((size_t)bb_ * 64 + h) * 512 + n0d + c] = cv.u;
    }
}

// ---------------- Kernel 2: edge coefficients (packed) + degree -------------
__global__ __launch_bounds__(256) void coefq_kernel(
    const float* __restrict__ A,     // [N, N, R]
    const float* __restrict__ gnn_w, // [R]
    const float* __restrict__ gnn_b, // [1]
    float* __restrict__ coefQ,       // [N/4][N][4]
    float* __restrict__ deg)         // [N], pre-zeroed
{
    __shared__ float ct[64 * 68];
    const int t = threadIdx.x;
    const int it = blockIdx.x >> 4, jt = blockIdx.x & 15;
    const int i_loc = t >> 2, chunk = t & 3;
    float gw[5];
    #pragma unroll
    for (int f = 0; f < 5; ++f) gw[f] = gnn_w[f];
    const float gb = gnn_b[0];

    const float* Ab = A + ((size_t)(it * 64 + i_loc) * 1024 + jt * 64 + chunk * 16) * 5;
    float buf[80];
    #pragma unroll
    for (int k = 0; k < 20; ++k)
        *(float4*)&buf[4 * k] = ((const float4*)Ab)[k];

    float cnt = 0.f;
    #pragma unroll
    for (int jj = 0; jj < 16; ++jj) {
        float s = 0.f, d = gb;
        #pragma unroll
        for (int f = 0; f < 5; ++f) { float vv = buf[5 * jj + f]; s += vv; d = fmaf(vv, gw[f], d); }
        float cf = (s > 0.f) ? (d >= 0.f ? d : 0.2f * d) : 0.f;
        ct[i_loc * 68 + chunk * 16 + jj] = cf;
        cnt += (s > 0.f) ? 1.f : 0.f;
    }
    cnt += __shfl_xor(cnt, 1);
    cnt += __shfl_xor(cnt, 2);
    if ((t & 3) == 0) atomicAdd(&deg[it * 64 + i_loc], cnt);
    __syncthreads();

    const int i_o = t & 63;
    #pragma unroll
    for (int p = 0; p < 4; ++p) {
        int jg = (t >> 6) + 4 * p;
        float4 v = *(const float4*)&ct[i_o * 68 + 4 * jg];
        ((float4*)coefQ)[(size_t)(jt * 16 + jg) * 1024 + it * 64 + i_o] = v;
    }
}

// ---------------- Kernel 3: MFMA GNN message pass + prediction head ---------
// Grid keyed it-major: it = blk>>5, b = blk&31. With round-robin XCD dispatch
// each XCD sees a fixed set of 4 b values (E16/ET slices stay L2-resident)
// and each coefQ it-slice is pulled into an XCD's L2 once and reused 4x.
__global__ __launch_bounds__(256, 2) void gnn_pred_kernel(
    const _Float16* __restrict__ E16,  // [B*N, H]
    const _Float16* __restrict__ ET,   // [B][H][N]
    const float* __restrict__ coefQ,   // [N/4][N][4]
    const float* __restrict__ deg,     // [N]
    const float* __restrict__ pred_w,  // [2H]
    const float* __restrict__ pred_b,  // [1]
    float* __restrict__ preds)         // [B*N], pre-zeroed
{
    __shared__ __align__(16) _Float16 tiles[2][4][64 * 64];  // 64 KB exactly
    const int tid  = threadIdx.x;
    const int w    = tid >> 6;
    const int lane = tid & 63;
    const int l31  = lane & 31;
    const int hi   = lane >> 5;
    const int it   = blockIdx.x >> 5;           // it-major (XCD locality)
    const int b    = blockIdx.x & 31;

    _Float16* EA = &tiles[0][w][0];
    _Float16* EB = &tiles[1][w][0];
    const float4* coefQ4 = (const float4*)coefQ;

    f16x8 eb[2][4];
    #pragma unroll
    for (int ni = 0; ni < 2; ++ni)
        #pragma unroll
        for (int kt = 0; kt < 4; ++kt)
            eb[ni][kt] = *(const f16x8*)(E16 +
                ((size_t)(b * 1024 + it * 64 + ni * 32 + l31) * 64 + 16 * kt + 8 * hi));

    f32x16 zero16 = {0,0,0,0,0,0,0,0,0,0,0,0,0,0,0,0};
    f32x16 oacc[2][2];
    #pragma unroll
    for (int mi = 0; mi < 2; ++mi)
        #pragma unroll
        for (int nh = 0; nh < 2; ++nh) oacc[mi][nh] = zero16;

    #pragma unroll 1
    for (int s = 0; s < 4; ++s) {
        const int jt = w * 4 + s;
        const _Float16* srcA = E16 + (size_t)(b * 1024 + jt * 64) * 64;
        const _Float16* srcB = ET + (size_t)b * 64 * 1024 + jt * 64;
        #pragma unroll
        for (int q = 0; q < 8; ++q) {
            int f = q * 64 + lane, r = f >> 3, c = f & 7;
            uint4 va = *(const uint4*)(srcA + r * 64 + c * 8);
            *(uint4*)(EA + r * 64 + ((c ^ (r & 7)) * 8)) = va;
            uint4 vb = *(const uint4*)(srcB + r * 1024 + c * 8);
            *(uint4*)(EB + r * 64 + ((c ^ (r & 7)) * 8)) = vb;
        }
        #pragma unroll 1
        for (int mj = 0; mj < 2; ++mj) {
            // A-frags of Ej for this 32-row half
            f16x8 af[4];
            #pragma unroll
            for (int kt = 0; kt < 4; ++kt)
                af[kt] = *(const f16x8*)(EA + (mj * 32 + l31) * 64 +
                                         (((2 * kt + hi) ^ (l31 & 7)) * 8));
            #pragma unroll
            for (int mi = 0; mi < 2; ++mi) {
                // S' = Ej . Ei^T  (16 regs live)
                f32x16 a = __builtin_amdgcn_mfma_f32_32x32x16_f16(af[0], eb[mi][0], zero16, 0, 0, 0);
                #pragma unroll
                for (int kt = 1; kt < 4; ++kt)
                    a = __builtin_amdgcn_mfma_f32_32x32x16_f16(af[kt], eb[mi][kt], a, 0, 0, 0);
                // P = S' * coef, in place
                #pragma unroll
                for (int rg = 0; rg < 4; ++rg) {
                    int j0 = jt * 64 + mj * 32 + 8 * rg + 4 * hi;
                    float4 cf = coefQ4[(size_t)(j0 >> 2) * 1024 + it * 64 + mi * 32 + l31];
                    a[4 * rg + 0] *= cf.x; a[4 * rg + 1] *= cf.y;
                    a[4 * rg + 2] *= cf.z; a[4 * rg + 3] *= cf.w;
                }
                // pack to A-layout fp16 frags (kk = local K-tile), lane^32 swap
                f16x8 pa[2];
                #pragma unroll
                for (int kk = 0; kk < 2; ++kk) {
                    const int rg = 2 * kk;
                    #pragma unroll
                    for (int c4 = 0; c4 < 4; ++c4) {
                        float own_lo = a[rg * 4 + c4];
                        float own_hi = a[(rg + 1) * 4 + c4];
                        float send = hi ? own_lo : own_hi;
                        float recv = __shfl_xor(send, 32);
                        float lo = hi ? recv : own_lo;
                        float hv = hi ? own_hi : recv;
                        pa[kk][c4]     = (_Float16)lo;
                        pa[kk][4 + c4] = (_Float16)hv;
                    }
                }
                // O += P . Ej  (ktj = 2*mj + kk), bb re-read from LDS per use
                #pragma unroll
                for (int nh = 0; nh < 2; ++nh)
                    #pragma unroll
                    for (int kk = 0; kk < 2; ++kk) {
                        const int ktj = 2 * mj + kk;
                        f16x8 bb = *(const f16x8*)(EB + (nh * 32 + l31) * 64 +
                                                   (((2 * ktj + hi) ^ (l31 & 7)) * 8));
                        oacc[mi][nh] = __builtin_amdgcn_mfma_f32_32x32x16_f16(
                            pa[kk], bb, oacc[mi][nh], 0, 0, 0);
                    }
            }
        }
    }

    const float pwh0 = pred_w[64 + l31];
    const float pwh1 = pred_w[96 + l31];
    #pragma unroll
    for (int mi = 0; mi < 2; ++mi)
        #pragma unroll
        for (int r = 0; r < 16; ++r) {
            float v = oacc[mi][0][r] * pwh0 + oacc[mi][1][r] * pwh1;
            v += __shfl_xor(v, 1);  v += __shfl_xor(v, 2);  v += __shfl_xor(v, 4);
            v += __shfl_xor(v, 8);  v += __shfl_xor(v, 16);
            int i_loc = mi * 32 + 8 * (r >> 2) + (r & 3) + 4 * hi;
            int gi = it * 64 + i_loc;
            if (l31 == 0) {
                float dg = deg[gi];
                atomicAdd(&preds[b * 1024 + gi], v * fast_rcp(dg));
            }
        }
    if (w == 0) {
        const float pb0 = pred_b[0];
        #pragma unroll
        for (int ni = 0; ni < 2; ++ni) {
            float dot = 0.f;
            #pragma unroll
            for (int kt = 0; kt < 4; ++kt)
                #pragma unroll
                for (int e = 0; e < 8; ++e)
                    dot = fmaf((float)eb[ni][kt][e], pred_w[16 * kt + 8 * hi + e], dot);
            dot += __shfl_xor(dot, 32);
            if (hi == 0)
                atomicAdd(&preds[b * 1024 + it * 64 + ni * 32 + l31], dot + pb0);
        }
    }
}

extern "C" void kernel_launch(void* const* d_in, const int* in_sizes, int n_in,
                              void* d_out, int out_size, void* d_ws, size_t ws_size,
                              hipStream_t stream) {
    const float* x      = (const float*)d_in[0];
    const float* A      = (const float*)d_in[1];
    const float* Wih    = (const float*)d_in[2];
    const float* Whh    = (const float*)d_in[3];
    const float* bih    = (const float*)d_in[4];
    const float* bhh    = (const float*)d_in[5];
    const float* attn_w = (const float*)d_in[6];
    const float* attn_b = (const float*)d_in[7];
    const float* gnn_w  = (const float*)d_in[8];
    const float* gnn_b  = (const float*)d_in[9];
    const float* pred_w = (const float*)d_in[10];
    const float* pred_b = (const float*)d_in[11];
    float* preds = (float*)d_out;

    // ws: E16 (4MB) | ET (4MB) | coefQ (4MB) | deg (4KB)
    _Float16* E16 = (_Float16*)d_ws;
    _Float16* ET  = E16 + (size_t)BNc * Hc;
    float* coefQ  = (float*)(ET + (size_t)BNc * Hc);
    float* deg    = coefQ + (size_t)Nc * Nc;

    hipMemsetAsync(preds, 0, (size_t)out_size * sizeof(float), stream);
    hipMemsetAsync(deg, 0, Nc * sizeof(float), stream);

    lstm_attn_kernel<<<BNc / 32, 128, 0, stream>>>(x, Wih, Whh, bih, bhh,
                                                   attn_w, attn_b, E16, ET);
    coefq_kernel<<<256, 256, 0, stream>>>(A, gnn_w, gnn_b, coefQ, deg);
    gnn_pred_kernel<<<Bc * (Nc / 64), 256, 0, stream>>>(E16, ET, coefQ, deg,
                                                        pred_w, pred_b, preds);
}